// Round 2
// baseline (330.650 us; speedup 1.0000x reference)
//
#include <hip/hip_runtime.h>
#include <hip/hip_bf16.h>

#define IMG 28
#define KX 784             // true K = 28*28
#define KT 25              // k-tiles of 32 -> K padded to 800
#define NT 13              // n-tiles of 16 -> N padded to 208; waves {3,2,2,2,2,2}
#define NH 200
#define NOUT 10
#define MT 32              // images per tile
#define AS 808             // bf16 elems per LDS A row (800 + 8 pad)
#define HSTRIDE 208        // fp32 elems per LDS h row
#define NTILES 4           // tiles per block; grid = 32768/(MT*NTILES) = 256 = 1/CU
#define F4T (MT * 196)     // 6272 float4 per x-tile

typedef __attribute__((ext_vector_type(8))) short bf16x8;
typedef __attribute__((ext_vector_type(4))) float f32x4;
typedef __attribute__((ext_vector_type(4))) short s16x4;

static __device__ __forceinline__ unsigned short bf16_bits(float v) {
    __hip_bfloat16 b = __float2bfloat16(v);
    return *(unsigned short*)&b;
}

// Raw barrier: lgkmcnt(0) drains MY ds_writes for cross-wave visibility, but
// does NOT drain vmcnt -- producer x-loads stay in flight across it.
#define FULL_BARRIER() do { \
    __builtin_amdgcn_sched_barrier(0); \
    asm volatile("s_waitcnt lgkmcnt(0)" ::: "memory"); \
    __builtin_amdgcn_s_barrier(); \
    __builtin_amdgcn_sched_barrier(0); \
} while (0)

// --- build W_eff = w0 composed with conv, packed in MFMA fragment order ---
// Bf[nt][kt][lane][j] = W_eff[nt*16+(lane&15)][kt*32+(lane>>4)*8+j], 0-padded.
__global__ void build_weff(const float* __restrict__ w0, const float* __restrict__ cw,
                           __hip_bfloat16* __restrict__ Bf) {
    int idx = blockIdx.x * blockDim.x + threadIdx.x;
    if (idx >= NT * KT * 512) return;
    int j = idx & 7, L = (idx >> 3) & 63, kt = (idx >> 9) % KT, nt = idx / (KT * 512);
    int n = nt * 16 + (L & 15);
    int k = kt * 32 + ((L >> 4) << 3) + j;
    float acc = 0.f;
    if (n < NH && k < KX) {
        int u = k / IMG, v = k - u * IMG;
#pragma unroll
        for (int i = 0; i < 3; ++i) {
#pragma unroll
            for (int jj = 0; jj < 3; ++jj) {
                int r = u - i, c = v - jj;
                if (r >= 0 && r < 26 && c >= 0 && c < 26)
                    acc += cw[i * 3 + jj] * w0[n * 676 + r * 26 + c];
            }
        }
    }
    Bf[idx] = __float2bfloat16(acc);
}

static __device__ __forceinline__ void cvt_store4(float4 v, int f, __hip_bfloat16* Ad) {
    int row = f / 196, col4 = f - row * 196;
    s16x4 p;
    p.x = (short)bf16_bits(v.x);
    p.y = (short)bf16_bits(v.y);
    p.z = (short)bf16_bits(v.z);
    p.w = (short)bf16_bits(v.w);
    *(s16x4*)(Ad + row * AS + col4 * 4) = p;
}

static __device__ __forceinline__ void preload_b(const bf16x8* bb, bf16x8 p[3][4], int ntn) {
#pragma unroll
    for (int n = 0; n < 3; ++n)
        if (n < ntn)
#pragma unroll
            for (int d = 0; d < 4; ++d) p[n][d] = bb[(n * KT + d) * 64];
}

// Consumer GEMM: clean vmcnt FIFO (B-loads only), B prefetched at distance 4.
template <int NTN>
static __device__ __forceinline__ void gemm_loop(
    const __hip_bfloat16* __restrict__ a0p, const __hip_bfloat16* __restrict__ a1p,
    const bf16x8* __restrict__ bb, bf16x8 p[3][4], f32x4 acc[2][3])
{
#pragma unroll
    for (int kt = 0; kt < KT; ++kt) {
        const int slot = kt & 3;
        bf16x8 b[3];
#pragma unroll
        for (int n = 0; n < NTN; ++n) {
            b[n] = p[n][slot];
            if (kt + 4 < KT) p[n][slot] = bb[(n * KT + kt + 4) * 64];
        }
        bf16x8 af0 = *(const bf16x8*)(a0p + kt * 32);
        bf16x8 af1 = *(const bf16x8*)(a1p + kt * 32);
#pragma unroll
        for (int n = 0; n < NTN; ++n) {
            acc[0][n] = __builtin_amdgcn_mfma_f32_16x16x32_bf16(af0, b[n], acc[0][n], 0, 0, 0);
            acc[1][n] = __builtin_amdgcn_mfma_f32_16x16x32_bf16(af1, b[n], acc[1][n], 0, 0, 0);
        }
    }
}

// Persistent pipelined block: waves 0-5 = GEMM consumers, waves 6-7 = x producers.
// LDS: A0/A1 double-buffer (103,424 B) + H (26,624 B) = 130,048 B -> 1 block/CU.
__global__ __launch_bounds__(512, 2) void gemm_fused_kernel(
    const float* __restrict__ x,            // [32768, 784]
    const __hip_bfloat16* __restrict__ Bf,  // fragment-packed W_eff
    const float* __restrict__ b0,           // [200]
    const float* __restrict__ w1,           // [10, 200]
    const float* __restrict__ b1,           // [10]
    float* __restrict__ out)                // [32768, 10]
{
    __shared__ __align__(16) char lds_raw[2 * MT * AS * 2 + MT * HSTRIDE * 4];
    __hip_bfloat16* A0 = (__hip_bfloat16*)lds_raw;
    __hip_bfloat16* A1 = A0 + MT * AS;
    float* H = (float*)(lds_raw + 2 * MT * AS * 2);

    const int tid  = threadIdx.x;
    const int wave = tid >> 6;
    const int L    = tid & 63;
    const int lm   = L & 15;
    const int q    = L >> 4;
    const int tile0 = blockIdx.x * NTILES;

    // ---- zero K-pad cols 784..799 of BOTH buffers (written once, never touched again)
    {
        int row = tid >> 4, c = KX + (tid & 15);
        ((unsigned short*)A0)[row * AS + c] = 0;
        ((unsigned short*)A1)[row * AS + c] = 0;
    }

    // ---- cooperative prologue: stage tile0 -> A0 (two-phase, all 8 waves) ----
    {
        const float4* xx = (const float4*)(x + (size_t)tile0 * MT * KX);
        float4 v[7];
#pragma unroll
        for (int t = 0; t < 7; ++t) v[t] = xx[tid + 512 * t];
        __builtin_amdgcn_sched_barrier(0);
#pragma unroll
        for (int t = 0; t < 7; ++t) cvt_store4(v[t], tid + 512 * t, A0);
        __builtin_amdgcn_sched_barrier(0);
#pragma unroll
        for (int t = 7; t < 13; ++t) {
            int f = tid + 512 * t;
            if (f < F4T) v[t - 7] = xx[f];
        }
        __builtin_amdgcn_sched_barrier(0);
#pragma unroll
        for (int t = 7; t < 13; ++t) {
            int f = tid + 512 * t;
            if (f < F4T) cvt_store4(v[t - 7], f, A0);
        }
    }

    // ---- roles: waves 0-5 consume (n-tiles {3,2,2,2,2,2}), waves 6-7 produce ----
    const bool producer = (wave >= 6);
    const int pl     = tid - 384;                          // 0..127 producer lane
    const int ntbase = (wave == 0) ? 0 : 3 + (wave - 1) * 2;
    const int ntn    = (wave == 0) ? 3 : 2;
    const bf16x8* bb = (const bf16x8*)Bf + (size_t)ntbase * KT * 64 + L;

    bf16x8 p[3][4];
    if (!producer) preload_b(bb, p, ntn);   // prologue x-loads already retired: clean FIFO

    for (int t = 0; t < NTILES; ++t) {
        __hip_bfloat16* Ab = (t & 1) ? A1 : A0;   // buffer consumed this tile
        __hip_bfloat16* Ad = (t & 1) ? A0 : A1;   // buffer produced for next tile
        const int tnext = (t + 1 < NTILES) ? (tile0 + t + 1) : tile0;
        const float4* xx1 = (const float4*)(x + (size_t)tnext * MT * KX);
        float4 va[25], vb[24];

        FULL_BARRIER();   // B1: A[t&1] staged & visible; H free for overwrite

        f32x4 acc[2][3];
        if (!producer) {
#pragma unroll
            for (int m = 0; m < 2; ++m)
#pragma unroll
                for (int n = 0; n < 3; ++n) acc[m][n] = (f32x4){0.f, 0.f, 0.f, 0.f};
            const __hip_bfloat16* a0p = Ab + lm * AS + q * 8;
            const __hip_bfloat16* a1p = Ab + (16 + lm) * AS + q * 8;
            if (ntn == 3) gemm_loop<3>(a0p, a1p, bb, p, acc);
            else          gemm_loop<2>(a0p, a1p, bb, p, acc);
            if (t + 1 < NTILES) preload_b(bb, p, ntn);   // next tile's kt=0..3, hidden here
            // epilogue: h = relu(acc + b0) -> H
#pragma unroll
            for (int n = 0; n < 3; ++n) {
                if (n < ntn) {
                    int col = (ntbase + n) * 16 + lm;
                    if (col < NH) {
                        float bv = b0[col];
#pragma unroll
                        for (int m = 0; m < 2; ++m)
#pragma unroll
                            for (int r = 0; r < 4; ++r) {
                                int mm = m * 16 + q * 4 + r;
                                float vv = acc[m][n][r] + bv;
                                H[mm * HSTRIDE + col] = vv > 0.f ? vv : 0.f;
                            }
                    }
                }
            }
        } else if (t + 1 < NTILES) {
            // issue batch 0 for tile t+1: stays in flight across B2 (raw barrier)
#pragma unroll
            for (int j = 0; j < 25; ++j) va[j] = xx1[j * 128 + pl];
            __builtin_amdgcn_sched_barrier(0);
        }

        FULL_BARRIER();   // B2: H visible; producer x-loads still in flight

        if (producer) {
            if (t + 1 < NTILES) {
                // convert batch 0 (stalls = pure BW wait, overlapped with FC1),
                // then issue + convert batch 1
#pragma unroll
                for (int j = 0; j < 25; ++j) cvt_store4(va[j], j * 128 + pl, Ad);
                __builtin_amdgcn_sched_barrier(0);
#pragma unroll
                for (int j = 0; j < 24; ++j) vb[j] = xx1[(25 + j) * 128 + pl];
                __builtin_amdgcn_sched_barrier(0);
#pragma unroll
                for (int j = 0; j < 24; ++j) cvt_store4(vb[j], (25 + j) * 128 + pl, Ad);
            }
        } else if (tid < MT * NOUT) {
            // FC1: out = h @ w1.T + b1 (fp32 VALU, waves 0-4)
            int i = tid / NOUT;
            int j = tid - i * NOUT;
            const float4* hrow = (const float4*)(H + i * HSTRIDE);
            const float4* wrow = (const float4*)(w1 + j * NH);
            float s = b1[j];
            float4 accv = {0.f, 0.f, 0.f, 0.f};
#pragma unroll 10
            for (int n = 0; n < NH / 4; ++n) {
                float4 h4 = hrow[n];
                float4 w4 = wrow[n];
                accv.x += h4.x * w4.x;
                accv.y += h4.y * w4.y;
                accv.z += h4.z * w4.z;
                accv.w += h4.w * w4.w;
            }
            s += (accv.x + accv.y) + (accv.z + accv.w);
            out[(size_t)((tile0 + t) * MT + i) * NOUT + j] = s;
        }
    }
}

extern "C" void kernel_launch(void* const* d_in, const int* in_sizes, int n_in,
                              void* d_out, int out_size, void* d_ws, size_t ws_size,
                              hipStream_t stream) {
    const float* x   = (const float*)d_in[0];
    const float* cw  = (const float*)d_in[1];
    const float* w0  = (const float*)d_in[2];
    const float* b0  = (const float*)d_in[3];
    const float* w1  = (const float*)d_in[4];
    const float* b1  = (const float*)d_in[5];
    float* out = (float*)d_out;

    __hip_bfloat16* Bf = (__hip_bfloat16*)d_ws;  // 13*25*512*2 = 332,800 B

    const int pack_elems = NT * KT * 512;
    build_weff<<<(pack_elems + 255) / 256, 256, 0, stream>>>(w0, cw, Bf);

    gemm_fused_kernel<<<32768 / (MT * NTILES), 512, 0, stream>>>(x, Bf, b0, w1, b1, out);
}

// Round 3
// 232.115 us; speedup vs baseline: 1.4245x; 1.4245x over previous
//
#include <hip/hip_runtime.h>
#include <hip/hip_bf16.h>

#define IMG 28
#define KX 784             // true K = 28*28
#define KT 25              // k-tiles of 32 -> K padded to 800
#define NT 13              // n-tiles of 16 -> N padded to 208; waves {3,2,2,2,2,2}
#define NH 200
#define NOUT 10
#define MT 32              // images per tile
#define AS 808             // bf16 elems per LDS A row (800 + 8 pad)
#define HSTRIDE 208        // fp32 elems per LDS h row
#define NTILES 4           // tiles per block; grid = 32768/(MT*NTILES) = 256 = 1/CU
#define F4T (MT * 196)     // 6272 float4 per x-tile

typedef __attribute__((ext_vector_type(8))) short bf16x8;
typedef __attribute__((ext_vector_type(4))) float f32x4;
typedef __attribute__((ext_vector_type(4))) short s16x4;

static __device__ __forceinline__ unsigned short bf16_bits(float v) {
    __hip_bfloat16 b = __float2bfloat16(v);
    return *(unsigned short*)&b;
}

// Raw barrier: lgkmcnt(0) drains MY ds_writes for cross-wave visibility, but
// does NOT drain vmcnt -- producer x-loads stay in flight across it.
#define FULL_BARRIER() do { \
    __builtin_amdgcn_sched_barrier(0); \
    asm volatile("s_waitcnt lgkmcnt(0)" ::: "memory"); \
    __builtin_amdgcn_s_barrier(); \
    __builtin_amdgcn_sched_barrier(0); \
} while (0)

// --- build W_eff = w0 composed with conv, packed in MFMA fragment order ---
// Bf[nt][kt][lane][j] = W_eff[nt*16+(lane&15)][kt*32+(lane>>4)*8+j], 0-padded.
__global__ void build_weff(const float* __restrict__ w0, const float* __restrict__ cw,
                           __hip_bfloat16* __restrict__ Bf) {
    int idx = blockIdx.x * blockDim.x + threadIdx.x;
    if (idx >= NT * KT * 512) return;
    int j = idx & 7, L = (idx >> 3) & 63, kt = (idx >> 9) % KT, nt = idx / (KT * 512);
    int n = nt * 16 + (L & 15);
    int k = kt * 32 + ((L >> 4) << 3) + j;
    float acc = 0.f;
    if (n < NH && k < KX) {
        int u = k / IMG, v = k - u * IMG;
#pragma unroll
        for (int i = 0; i < 3; ++i) {
#pragma unroll
            for (int jj = 0; jj < 3; ++jj) {
                int r = u - i, c = v - jj;
                if (r >= 0 && r < 26 && c >= 0 && c < 26)
                    acc += cw[i * 3 + jj] * w0[n * 676 + r * 26 + c];
            }
        }
    }
    Bf[idx] = __float2bfloat16(acc);
}

static __device__ __forceinline__ void cvt_store4(float4 v, int f, __hip_bfloat16* Ad) {
    int row = f / 196, col4 = f - row * 196;
    s16x4 p;
    p.x = (short)bf16_bits(v.x);
    p.y = (short)bf16_bits(v.y);
    p.z = (short)bf16_bits(v.z);
    p.w = (short)bf16_bits(v.w);
    *(s16x4*)(Ad + row * AS + col4 * 4) = p;
}

static __device__ __forceinline__ void preload_b(const bf16x8* bb, bf16x8 p[3][4], int ntn) {
#pragma unroll
    for (int n = 0; n < 3; ++n)
        if (n < ntn)
#pragma unroll
            for (int d = 0; d < 4; ++d) p[n][d] = bb[(n * KT + d) * 64];
}

// Consumer GEMM: clean vmcnt FIFO (B-loads only), B prefetched at distance 4.
template <int NTN>
static __device__ __forceinline__ void gemm_loop(
    const __hip_bfloat16* __restrict__ a0p, const __hip_bfloat16* __restrict__ a1p,
    const bf16x8* __restrict__ bb, bf16x8 p[3][4], f32x4 acc[2][3])
{
#pragma unroll
    for (int kt = 0; kt < KT; ++kt) {
        const int slot = kt & 3;
        bf16x8 b[3];
#pragma unroll
        for (int n = 0; n < NTN; ++n) {
            b[n] = p[n][slot];
            if (kt + 4 < KT) p[n][slot] = bb[(n * KT + kt + 4) * 64];
        }
        bf16x8 af0 = *(const bf16x8*)(a0p + kt * 32);
        bf16x8 af1 = *(const bf16x8*)(a1p + kt * 32);
#pragma unroll
        for (int n = 0; n < NTN; ++n) {
            acc[0][n] = __builtin_amdgcn_mfma_f32_16x16x32_bf16(af0, b[n], acc[0][n], 0, 0, 0);
            acc[1][n] = __builtin_amdgcn_mfma_f32_16x16x32_bf16(af1, b[n], acc[1][n], 0, 0, 0);
        }
    }
}

// Persistent pipelined block: waves 0-5 = GEMM consumers, waves 6-7 = x producers.
// LDS: A0/A1 double-buffer (103,424 B) + H (26,624 B) = 130,048 B -> 1 block/CU.
__global__ __launch_bounds__(512, 2) void gemm_fused_kernel(
    const float* __restrict__ x,            // [32768, 784]
    const __hip_bfloat16* __restrict__ Bf,  // fragment-packed W_eff
    const float* __restrict__ b0,           // [200]
    const float* __restrict__ w1,           // [10, 200]
    const float* __restrict__ b1,           // [10]
    float* __restrict__ out)                // [32768, 10]
{
    __shared__ __align__(16) char lds_raw[2 * MT * AS * 2 + MT * HSTRIDE * 4];
    __hip_bfloat16* A0 = (__hip_bfloat16*)lds_raw;
    __hip_bfloat16* A1 = A0 + MT * AS;
    float* H = (float*)(lds_raw + 2 * MT * AS * 2);

    const int tid  = threadIdx.x;
    const int wave = tid >> 6;
    const int L    = tid & 63;
    const int lm   = L & 15;
    const int q    = L >> 4;
    const int tile0 = blockIdx.x * NTILES;

    // ---- zero K-pad cols 784..799 of BOTH buffers (written once, never touched again)
    {
        int row = tid >> 4, c = KX + (tid & 15);
        ((unsigned short*)A0)[row * AS + c] = 0;
        ((unsigned short*)A1)[row * AS + c] = 0;
    }

    // ---- cooperative prologue: stage tile0 -> A0 (two-phase, all 8 waves) ----
    {
        const float4* xx = (const float4*)(x + (size_t)tile0 * MT * KX);
        float4 v[7];
#pragma unroll
        for (int t = 0; t < 7; ++t) v[t] = xx[tid + 512 * t];
        __builtin_amdgcn_sched_barrier(0);
#pragma unroll
        for (int t = 0; t < 7; ++t) cvt_store4(v[t], tid + 512 * t, A0);
        __builtin_amdgcn_sched_barrier(0);
#pragma unroll
        for (int t = 7; t < 13; ++t) {
            int f = tid + 512 * t;
            if (f < F4T) v[t - 7] = xx[f];
        }
        __builtin_amdgcn_sched_barrier(0);
#pragma unroll
        for (int t = 7; t < 13; ++t) {
            int f = tid + 512 * t;
            if (f < F4T) cvt_store4(v[t - 7], f, A0);
        }
    }

    // ---- roles: waves 0-5 consume (n-tiles {3,2,2,2,2,2}), waves 6-7 produce ----
    const bool producer = (wave >= 6);
    const int pl     = tid - 384;                          // 0..127 producer lane
    const int ntbase = (wave == 0) ? 0 : 3 + (wave - 1) * 2;
    const int ntn    = (wave == 0) ? 3 : 2;
    const bf16x8* bb = (const bf16x8*)Bf + (size_t)ntbase * KT * 64 + L;

    bf16x8 p[3][4];
    if (!producer) preload_b(bb, p, ntn);   // prologue x-loads already retired: clean FIFO

    for (int t = 0; t < NTILES; ++t) {
        __hip_bfloat16* Ab = (t & 1) ? A1 : A0;   // buffer consumed this tile
        __hip_bfloat16* Ad = (t & 1) ? A0 : A1;   // buffer produced for next tile
        const int tnext = (t + 1 < NTILES) ? (tile0 + t + 1) : tile0;
        const float4* xx1 = (const float4*)(x + (size_t)tnext * MT * KX);

        FULL_BARRIER();   // B1: A[t&1] staged & visible; H free for overwrite

        if (!producer) {
            f32x4 acc[2][3];
#pragma unroll
            for (int m = 0; m < 2; ++m)
#pragma unroll
                for (int n = 0; n < 3; ++n) acc[m][n] = (f32x4){0.f, 0.f, 0.f, 0.f};
            const __hip_bfloat16* a0p = Ab + lm * AS + q * 8;
            const __hip_bfloat16* a1p = Ab + (16 + lm) * AS + q * 8;
            if (ntn == 3) gemm_loop<3>(a0p, a1p, bb, p, acc);
            else          gemm_loop<2>(a0p, a1p, bb, p, acc);
            if (t + 1 < NTILES) preload_b(bb, p, ntn);   // next tile's kt=0..3, hidden here
            // epilogue: h = relu(acc + b0) -> H
#pragma unroll
            for (int n = 0; n < 3; ++n) {
                if (n < ntn) {
                    int col = (ntbase + n) * 16 + lm;
                    if (col < NH) {
                        float bv = b0[col];
#pragma unroll
                        for (int m = 0; m < 2; ++m)
#pragma unroll
                            for (int r = 0; r < 4; ++r) {
                                int mm = m * 16 + q * 4 + r;
                                float vv = acc[m][n][r] + bv;
                                H[mm * HSTRIDE + col] = vv > 0.f ? vv : 0.f;
                            }
                    }
                }
            }
        } else if (t + 1 < NTILES) {
            // ---- producer: stage tile t+1 -> Ad as 7 batches of 7 float4/lane ----
            // Double-buffered registers (14 float4 live = 56 VGPR, NO spill);
            // batch g+1's 7 loads (14 KB/CU across 2 waves) in flight while
            // batch g converts -> sustains fair-share HBM BW continuously.
            float4 va[7], vb[7];
#pragma unroll
            for (int j = 0; j < 7; ++j) va[j] = xx1[j * 128 + pl];
            __builtin_amdgcn_sched_barrier(0);
#pragma unroll
            for (int g = 0; g < 7; ++g) {           // fully unrolled: g is compile-time
                if (g + 1 < 7) {
                    if (g & 1) {
#pragma unroll
                        for (int j = 0; j < 7; ++j) va[j] = xx1[((g + 1) * 7 + j) * 128 + pl];
                    } else {
#pragma unroll
                        for (int j = 0; j < 7; ++j) vb[j] = xx1[((g + 1) * 7 + j) * 128 + pl];
                    }
                }
                __builtin_amdgcn_sched_barrier(0);
                if (g & 1) {
#pragma unroll
                    for (int j = 0; j < 7; ++j) cvt_store4(vb[j], (g * 7 + j) * 128 + pl, Ad);
                } else {
#pragma unroll
                    for (int j = 0; j < 7; ++j) cvt_store4(va[j], (g * 7 + j) * 128 + pl, Ad);
                }
                __builtin_amdgcn_sched_barrier(0);
            }
        }

        FULL_BARRIER();   // B2: H visible; producer ds_writes to Ad drained (lgkmcnt)

        if (!producer && tid < MT * NOUT) {
            // FC1: out = h @ w1.T + b1 (fp32 VALU, waves 0-4)
            int i = tid / NOUT;
            int j = tid - i * NOUT;
            const float4* hrow = (const float4*)(H + i * HSTRIDE);
            const float4* wrow = (const float4*)(w1 + j * NH);
            float s = b1[j];
            float4 accv = {0.f, 0.f, 0.f, 0.f};
#pragma unroll 10
            for (int n = 0; n < NH / 4; ++n) {
                float4 h4 = hrow[n];
                float4 w4 = wrow[n];
                accv.x += h4.x * w4.x;
                accv.y += h4.y * w4.y;
                accv.z += h4.z * w4.z;
                accv.w += h4.w * w4.w;
            }
            s += (accv.x + accv.y) + (accv.z + accv.w);
            out[(size_t)((tile0 + t) * MT + i) * NOUT + j] = s;
        }
    }
}

extern "C" void kernel_launch(void* const* d_in, const int* in_sizes, int n_in,
                              void* d_out, int out_size, void* d_ws, size_t ws_size,
                              hipStream_t stream) {
    const float* x   = (const float*)d_in[0];
    const float* cw  = (const float*)d_in[1];
    const float* w0  = (const float*)d_in[2];
    const float* b0  = (const float*)d_in[3];
    const float* w1  = (const float*)d_in[4];
    const float* b1  = (const float*)d_in[5];
    float* out = (float*)d_out;

    __hip_bfloat16* Bf = (__hip_bfloat16*)d_ws;  // 13*25*512*2 = 332,800 B

    const int pack_elems = NT * KT * 512;
    build_weff<<<(pack_elems + 255) / 256, 256, 0, stream>>>(w0, cw, Bf);

    gemm_fused_kernel<<<32768 / (MT * NTILES), 512, 0, stream>>>(x, Bf, b0, w1, b1, out);
}